// Round 3
// baseline (1061.099 us; speedup 1.0000x reference)
//
#include <hip/hip_runtime.h>
#include <cstdint>
#include <cstddef>

#define EPS 1e-5f

typedef _Float16 f16;
typedef __attribute__((ext_vector_type(8))) _Float16 f16x8;
typedef __attribute__((ext_vector_type(4))) _Float16 f16x4;
typedef __attribute__((ext_vector_type(4))) float f32x4;

__device__ __forceinline__ float4 ld4(const float* p) { return *(const float4*)p; }
__device__ __forceinline__ void st4(float* p, float4 v) { *(float4*)p = v; }

// ---------------------------------------------------------------------------
// QKV projection: out[4096,384](f16) = s[4096,128] @ W, q gets *SCALE.
// grid=(64, 6, 3) z selects q/k/v. 64x64 tile, BK=32, micro 4x4.
// ---------------------------------------------------------------------------
__launch_bounds__(256)
__global__ void qkv_kernel(const float* __restrict__ A,
                           const float* __restrict__ Wq,
                           const float* __restrict__ Wk,
                           const float* __restrict__ Wv,
                           f16* __restrict__ qo, f16* __restrict__ ko,
                           f16* __restrict__ vo) {
    __shared__ float As[32 * 68];
    __shared__ float Bs[32 * 68];
    const int tid = threadIdx.x;
    const int bx = blockIdx.x, by = blockIdx.y, z = blockIdx.z;
    const float* Wp = (z == 0) ? Wq : ((z == 1) ? Wk : Wv);
    f16* outp = (z == 0) ? qo : ((z == 1) ? ko : vo);
    const float alpha = (z == 0) ? 0.05103103630798288f : 1.0f;
    const int tx = tid & 15, ty = tid >> 4;
    float acc[4][4] = {};
    for (int k0 = 0; k0 < 128; k0 += 32) {
        __syncthreads();
#pragma unroll
        for (int itr = 0; itr < 2; ++itr) {
            int idx = tid + itr * 256;
            int r = idx >> 3, c4 = idx & 7;
            float4 a = ld4(&A[(size_t)(bx * 64 + r) * 128 + k0 + c4 * 4]);
            As[(c4 * 4 + 0) * 68 + r] = a.x;
            As[(c4 * 4 + 1) * 68 + r] = a.y;
            As[(c4 * 4 + 2) * 68 + r] = a.z;
            As[(c4 * 4 + 3) * 68 + r] = a.w;
            int kb = idx >> 4, n4 = (idx & 15) * 4;
            st4(&Bs[kb * 68 + n4], ld4(&Wp[(size_t)(k0 + kb) * 384 + by * 64 + n4]));
        }
        __syncthreads();
#pragma unroll
        for (int kk = 0; kk < 32; ++kk) {
            float4 av = ld4(&As[kk * 68 + ty * 4]);
            float4 bv = ld4(&Bs[kk * 68 + tx * 4]);
            acc[0][0] = fmaf(av.x, bv.x, acc[0][0]);
            acc[0][1] = fmaf(av.x, bv.y, acc[0][1]);
            acc[0][2] = fmaf(av.x, bv.z, acc[0][2]);
            acc[0][3] = fmaf(av.x, bv.w, acc[0][3]);
            acc[1][0] = fmaf(av.y, bv.x, acc[1][0]);
            acc[1][1] = fmaf(av.y, bv.y, acc[1][1]);
            acc[1][2] = fmaf(av.y, bv.z, acc[1][2]);
            acc[1][3] = fmaf(av.y, bv.w, acc[1][3]);
            acc[2][0] = fmaf(av.z, bv.x, acc[2][0]);
            acc[2][1] = fmaf(av.z, bv.y, acc[2][1]);
            acc[2][2] = fmaf(av.z, bv.z, acc[2][2]);
            acc[2][3] = fmaf(av.z, bv.w, acc[2][3]);
            acc[3][0] = fmaf(av.w, bv.x, acc[3][0]);
            acc[3][1] = fmaf(av.w, bv.y, acc[3][1]);
            acc[3][2] = fmaf(av.w, bv.z, acc[3][2]);
            acc[3][3] = fmaf(av.w, bv.w, acc[3][3]);
        }
    }
#pragma unroll
    for (int mi = 0; mi < 4; ++mi) {
        f16x4 hv;
        hv[0] = (f16)(acc[mi][0] * alpha);
        hv[1] = (f16)(acc[mi][1] * alpha);
        hv[2] = (f16)(acc[mi][2] * alpha);
        hv[3] = (f16)(acc[mi][3] * alpha);
        *(f16x4*)&outp[(size_t)(bx * 64 + ty * 4 + mi) * 384 + by * 64 + tx * 4] = hv;
    }
}

// ---------------------------------------------------------------------------
// Scores: E[b,h,i,j] = exp( qk + p@W2d + b2d ).  No-max softmax numerator.
// Block = (jchunk64, itile16, b); 4 waves = 4 j-subtiles of 16.
// Per-lane (i,j) mapping == MFMA C-frag layout, so pbias accumulates
// directly into the MFMA accumulator. p streamed from global (512 MB).
// ---------------------------------------------------------------------------
__launch_bounds__(256)
__global__ void scores_kernel(const f16* __restrict__ qw,
                              const f16* __restrict__ kw,
                              const float* __restrict__ p,
                              const float* __restrict__ w2d,
                              const float* __restrict__ b2d,
                              f16* __restrict__ E) {
    const int tid = threadIdx.x;
    const int wv = tid >> 6, lane = tid & 63;
    const int g = lane >> 4, lj = lane & 15;
    const int jc = blockIdx.x, it = blockIdx.y, b = blockIdx.z;
    const int i0 = it * 16, j0 = jc * 64 + wv * 16;

    // A-frags (q): lane holds row i0+lj, k = h*32 + g*8 + e
    f16x8 qf[12];
#pragma unroll
    for (int h = 0; h < 12; ++h)
        qf[h] = *(const f16x8*)&qw[((size_t)(i0 + lj) * 8 + b) * 384 + h * 32 + g * 8];

    f32x4 acc[12];
#pragma unroll
    for (int h = 0; h < 12; ++h) {
        float bb = b2d[h];
        acc[h][0] = bb; acc[h][1] = bb; acc[h][2] = bb; acc[h][3] = bb;
    }

    // pair-bias: lane covers pairs (i=i0+g*4+r, j=j0+lj) — the C-frag cells
#pragma unroll
    for (int r = 0; r < 4; ++r) {
        const float* prow = p + (((size_t)b * 512 + i0 + g * 4 + r) * 512 + j0 + lj) * 64;
#pragma unroll
        for (int hf = 0; hf < 2; ++hf) {
            float4 pb[8];
#pragma unroll
            for (int c = 0; c < 8; ++c) pb[c] = ld4(prow + hf * 32 + c * 4);
            const float* pf = (const float*)pb;
#pragma unroll
            for (int e = 0; e < 32; ++e) {
                float pe = pf[e];
                const float* wrow = &w2d[(hf * 32 + e) * 12];
#pragma unroll
                for (int h = 0; h < 12; ++h) acc[h][r] = fmaf(pe, wrow[h], acc[h][r]);
            }
        }
    }

    // QK^T via MFMA, K=32 = head_dim (one MFMA per head)
    f16x8 kf = *(const f16x8*)&kw[((size_t)(j0 + lj) * 8 + b) * 384 + g * 8];
#pragma unroll
    for (int h = 0; h < 12; ++h) {
        f16x8 kn = kf;
        if (h < 11)
            kn = *(const f16x8*)&kw[((size_t)(j0 + lj) * 8 + b) * 384 + (h + 1) * 32 + g * 8];
        acc[h] = __builtin_amdgcn_mfma_f32_16x16x32_f16(qf[h], kf, acc[h], 0, 0, 0);
        kf = kn;
    }

    // exp + store fp16 numerators
#pragma unroll
    for (int h = 0; h < 12; ++h) {
        size_t ebase = (size_t)(b * 12 + h) * 512;
#pragma unroll
        for (int r = 0; r < 4; ++r) {
            E[(ebase + i0 + g * 4 + r) * 512 + j0 + lj] = (f16)__expf(acc[h][r]);
        }
    }
}

// ---------------------------------------------------------------------------
// PV: o[b,h,i,d] = (E @ v_h) / rowsum(E).  Block = (b*12+h, itile64),
// 4 waves = 4 i-subtiles of 16.  v_h staged transposed [d][j] in LDS so
// B-frags are single ds_read_b128.  l from A-frag sums (consistent ratio).
// ---------------------------------------------------------------------------
__launch_bounds__(256)
__global__ void pv_kernel(const f16* __restrict__ E,
                          const f16* __restrict__ vw,
                          float* __restrict__ o) {
    __shared__ f16 vt[32][520];
    const int tid = threadIdx.x;
    const int bh = blockIdx.x;
    const int b = bh / 12, h = bh % 12;
    const int wv = tid >> 6, lane = tid & 63;
    const int g = lane >> 4, lj = lane & 15;
    const int i0 = blockIdx.y * 64 + wv * 16;

    // stage v_h transposed: vt[d][j]
#pragma unroll
    for (int itr = 0; itr < 8; ++itr) {
        int jl = itr * 64 + (tid >> 2);
        int dc = (tid & 3) * 8;
        f16x8 sv = *(const f16x8*)&vw[((size_t)jl * 8 + b) * 384 + h * 32 + dc];
#pragma unroll
        for (int dd = 0; dd < 8; ++dd) vt[dc + dd][jl] = sv[dd];
    }
    __syncthreads();

    f32x4 acc0 = {}, acc1 = {};
    float lsum = 0.f;
    const f16* Erow = &E[((size_t)bh * 512 + i0 + lj) * 512];
#pragma unroll
    for (int ks = 0; ks < 16; ++ks) {
        f16x8 af = *(const f16x8*)&Erow[ks * 32 + g * 8];
        f16x8 b0 = *(const f16x8*)&vt[lj][ks * 32 + g * 8];
        f16x8 b1 = *(const f16x8*)&vt[16 + lj][ks * 32 + g * 8];
        acc0 = __builtin_amdgcn_mfma_f32_16x16x32_f16(af, b0, acc0, 0, 0, 0);
        acc1 = __builtin_amdgcn_mfma_f32_16x16x32_f16(af, b1, acc1, 0, 0, 0);
#pragma unroll
        for (int d = 0; d < 8; ++d) lsum += (float)af[d];
    }
    lsum += __shfl_xor(lsum, 16);
    lsum += __shfl_xor(lsum, 32);   // lane L now holds l[i = L&15]

#pragma unroll
    for (int r = 0; r < 4; ++r) {
        float lr = __shfl(lsum, g * 4 + r);
        float inv = 1.0f / lr;
        size_t orow = ((size_t)(i0 + g * 4 + r) * 8 + b) * 384 + h * 32;
        o[orow + lj] = acc0[r] * inv;
        o[orow + 16 + lj] = acc1[r] * inv;
    }
}

// ---------------------------------------------------------------------------
// Fused GEMM (+bias) + residual + LayerNorm.  N=128 fixed (full LN row per
// block).  Tile 32 rows x 128 cols, BK=32, micro 4x4, block 256.
// out = LN(resid + A@W + bias) * g + be
// ---------------------------------------------------------------------------
__launch_bounds__(256)
__global__ void gemm_ln_kernel(const float* __restrict__ A, int K,
                               const float* __restrict__ Wm,
                               const float* __restrict__ bias,
                               const float* __restrict__ resid,
                               const float* __restrict__ gam,
                               const float* __restrict__ bet,
                               float* __restrict__ out) {
    __shared__ float As[32][36];
    __shared__ float Bs[32][132];
    const int tid = threadIdx.x;
    const int bx = blockIdx.x;
    const int tx = tid & 31, ty = tid >> 5;
    float acc[4][4] = {};
    for (int k0 = 0; k0 < K; k0 += 32) {
        __syncthreads();
        {
            int r = tid >> 3, c4 = tid & 7;
            float4 a = ld4(&A[(size_t)(bx * 32 + r) * K + k0 + c4 * 4]);
            As[c4 * 4 + 0][r] = a.x;
            As[c4 * 4 + 1][r] = a.y;
            As[c4 * 4 + 2][r] = a.z;
            As[c4 * 4 + 3][r] = a.w;
#pragma unroll
            for (int itr = 0; itr < 4; ++itr) {
                int idx = tid + itr * 256;
                int kb = idx >> 5, n4 = (idx & 31) * 4;
                st4(&Bs[kb][n4], ld4(&Wm[(size_t)(k0 + kb) * 128 + n4]));
            }
        }
        __syncthreads();
#pragma unroll
        for (int kk = 0; kk < 32; ++kk) {
            float4 av = ld4(&As[kk][ty * 4]);
            float4 bv = ld4(&Bs[kk][tx * 4]);
            acc[0][0] = fmaf(av.x, bv.x, acc[0][0]);
            acc[0][1] = fmaf(av.x, bv.y, acc[0][1]);
            acc[0][2] = fmaf(av.x, bv.z, acc[0][2]);
            acc[0][3] = fmaf(av.x, bv.w, acc[0][3]);
            acc[1][0] = fmaf(av.y, bv.x, acc[1][0]);
            acc[1][1] = fmaf(av.y, bv.y, acc[1][1]);
            acc[1][2] = fmaf(av.y, bv.z, acc[1][2]);
            acc[1][3] = fmaf(av.y, bv.w, acc[1][3]);
            acc[2][0] = fmaf(av.z, bv.x, acc[2][0]);
            acc[2][1] = fmaf(av.z, bv.y, acc[2][1]);
            acc[2][2] = fmaf(av.z, bv.z, acc[2][2]);
            acc[2][3] = fmaf(av.z, bv.w, acc[2][3]);
            acc[3][0] = fmaf(av.w, bv.x, acc[3][0]);
            acc[3][1] = fmaf(av.w, bv.y, acc[3][1]);
            acc[3][2] = fmaf(av.w, bv.z, acc[3][2]);
            acc[3][3] = fmaf(av.w, bv.w, acc[3][3]);
        }
    }
    // epilogue: +bias +resid, per-row LN (row cols live in 32 lanes)
    float4 bb = ld4(&bias[tx * 4]);
    float4 gg = ld4(&gam[tx * 4]);
    float4 be4 = ld4(&bet[tx * 4]);
#pragma unroll
    for (int mi = 0; mi < 4; ++mi) {
        int row = bx * 32 + ty * 4 + mi;
        float4 r4 = ld4(&resid[(size_t)row * 128 + tx * 4]);
        float4 y;
        y.x = acc[mi][0] + bb.x + r4.x;
        y.y = acc[mi][1] + bb.y + r4.y;
        y.z = acc[mi][2] + bb.z + r4.z;
        y.w = acc[mi][3] + bb.w + r4.w;
        float s = y.x + y.y + y.z + y.w;
        float sq = y.x * y.x + y.y * y.y + y.z * y.z + y.w * y.w;
#pragma unroll
        for (int m = 1; m <= 16; m <<= 1) {
            s += __shfl_xor(s, m);
            sq += __shfl_xor(sq, m);
        }
        float mean = s * (1.f / 128.f);
        float var = sq * (1.f / 128.f) - mean * mean;
        float rs = rsqrtf(var + EPS);
        float4 w;
        w.x = (y.x - mean) * rs * gg.x + be4.x;
        w.y = (y.y - mean) * rs * gg.y + be4.y;
        w.z = (y.z - mean) * rs * gg.z + be4.z;
        w.w = (y.w - mean) * rs * gg.w + be4.w;
        st4(&out[(size_t)row * 128 + tx * 4], w);
    }
}

// ---------------------------------------------------------------------------
// FFN1: h = relu([s1, x] @ W1 + b1).  A is concat of A1 (rowlen K1) and A2.
// grid=(64, 8), 64x64 tile, BK=32.
// ---------------------------------------------------------------------------
template<bool RELU>
__launch_bounds__(256)
__global__ void gemm_bias_kernel(const float* __restrict__ A1,
                                 const float* __restrict__ A2, int K1,
                                 const float* __restrict__ W,
                                 const float* __restrict__ bias,
                                 float* __restrict__ out,
                                 int N, int K) {
    __shared__ float As[32 * 68];
    __shared__ float Bs[32 * 68];
    const int tid = threadIdx.x;
    const int bx = blockIdx.x, by = blockIdx.y;
    const int tx = tid & 15, ty = tid >> 4;
    float acc[4][4] = {};
    for (int k0 = 0; k0 < K; k0 += 32) {
        __syncthreads();
#pragma unroll
        for (int itr = 0; itr < 2; ++itr) {
            int idx = tid + itr * 256;
            int r = idx >> 3, c4 = idx & 7;
            int kk = k0 + c4 * 4;
            const float* src; int rl, kl;
            if (kk < K1) { src = A1; rl = K1; kl = kk; }
            else         { src = A2; rl = K - K1; kl = kk - K1; }
            float4 a = ld4(&src[(size_t)(bx * 64 + r) * rl + kl]);
            As[(c4 * 4 + 0) * 68 + r] = a.x;
            As[(c4 * 4 + 1) * 68 + r] = a.y;
            As[(c4 * 4 + 2) * 68 + r] = a.z;
            As[(c4 * 4 + 3) * 68 + r] = a.w;
            int kb = idx >> 4, n4 = (idx & 15) * 4;
            st4(&Bs[kb * 68 + n4], ld4(&W[(size_t)(k0 + kb) * N + by * 64 + n4]));
        }
        __syncthreads();
#pragma unroll
        for (int kk2 = 0; kk2 < 32; ++kk2) {
            float4 av = ld4(&As[kk2 * 68 + ty * 4]);
            float4 bv = ld4(&Bs[kk2 * 68 + tx * 4]);
            acc[0][0] = fmaf(av.x, bv.x, acc[0][0]);
            acc[0][1] = fmaf(av.x, bv.y, acc[0][1]);
            acc[0][2] = fmaf(av.x, bv.z, acc[0][2]);
            acc[0][3] = fmaf(av.x, bv.w, acc[0][3]);
            acc[1][0] = fmaf(av.y, bv.x, acc[1][0]);
            acc[1][1] = fmaf(av.y, bv.y, acc[1][1]);
            acc[1][2] = fmaf(av.y, bv.z, acc[1][2]);
            acc[1][3] = fmaf(av.y, bv.w, acc[1][3]);
            acc[2][0] = fmaf(av.z, bv.x, acc[2][0]);
            acc[2][1] = fmaf(av.z, bv.y, acc[2][1]);
            acc[2][2] = fmaf(av.z, bv.z, acc[2][2]);
            acc[2][3] = fmaf(av.z, bv.w, acc[2][3]);
            acc[3][0] = fmaf(av.w, bv.x, acc[3][0]);
            acc[3][1] = fmaf(av.w, bv.y, acc[3][1]);
            acc[3][2] = fmaf(av.w, bv.z, acc[3][2]);
            acc[3][3] = fmaf(av.w, bv.w, acc[3][3]);
        }
    }
    float4 bb = {0.f, 0.f, 0.f, 0.f};
    if (bias) bb = ld4(&bias[by * 64 + tx * 4]);
#pragma unroll
    for (int mi = 0; mi < 4; ++mi) {
        float4 y;
        y.x = acc[mi][0] + bb.x;
        y.y = acc[mi][1] + bb.y;
        y.z = acc[mi][2] + bb.z;
        y.w = acc[mi][3] + bb.w;
        if (RELU) {
            y.x = fmaxf(y.x, 0.f); y.y = fmaxf(y.y, 0.f);
            y.z = fmaxf(y.z, 0.f); y.w = fmaxf(y.w, 0.f);
        }
        st4(&out[(size_t)(bx * 64 + ty * 4 + mi) * N + by * 64 + tx * 4], y);
    }
}

// ---------------------------------------------------------------------------
extern "C" void kernel_launch(void* const* d_in, const int* in_sizes, int n_in,
                              void* d_out, int out_size, void* d_ws, size_t ws_size,
                              hipStream_t stream) {
    const float* s   = (const float*)d_in[0];
    const float* x   = (const float*)d_in[1];
    const float* p   = (const float*)d_in[2];
    const float* Wq  = (const float*)d_in[3];
    const float* Wk  = (const float*)d_in[4];
    const float* Wv  = (const float*)d_in[5];
    const float* Wo  = (const float*)d_in[6];
    const float* bo  = (const float*)d_in[7];
    const float* W2d = (const float*)d_in[8];
    const float* b2d = (const float*)d_in[9];
    const float* W1  = (const float*)d_in[10];
    const float* b1  = (const float*)d_in[11];
    const float* W2  = (const float*)d_in[12];
    const float* b2  = (const float*)d_in[13];
    const float* g1  = (const float*)d_in[14];
    const float* be1 = (const float*)d_in[15];
    const float* g2  = (const float*)d_in[16];
    const float* be2 = (const float*)d_in[17];
    float* out = (float*)d_out;

    char* W = (char*)d_ws;
    f16* q_ws = (f16*)W;                         // 4096*384 f16 (3.15 MB)
    f16* k_ws = q_ws + 4096 * 384;               // 3.15 MB
    f16* v_ws = (f16*)(W + 6291456);             // 3.15 MB
    f16* E_ws = (f16*)(W + 9437184);             // 8*12*512*512 f16 (50.3 MB)
    float* o_ws = (float*)W;                     // overlays q,k after scores
    float* s1   = (float*)(W + 9437184 + 50331648);
    float* h_ws = s1 + 4096 * 128;

    dim3 blk(256);
    qkv_kernel<<<dim3(64, 6, 3), blk, 0, stream>>>(s, Wq, Wk, Wv, q_ws, k_ws, v_ws);
    scores_kernel<<<dim3(8, 32, 8), blk, 0, stream>>>(q_ws, k_ws, p, W2d, b2d, E_ws);
    pv_kernel<<<dim3(96, 8), blk, 0, stream>>>(E_ws, v_ws, o_ws);
    gemm_ln_kernel<<<dim3(128), blk, 0, stream>>>(o_ws, 384, Wo, bo, s, g1, be1, s1);
    gemm_bias_kernel<true><<<dim3(64, 8), blk, 0, stream>>>(s1, x, 128, W1, b1, h_ws, 512, 192);
    gemm_ln_kernel<<<dim3(128), blk, 0, stream>>>(h_ws, 512, W2, b2, s1, g2, be2, out);
}